// Round 2
// baseline (175.212 us; speedup 1.0000x reference)
//
#include <hip/hip_runtime.h>
#include <math.h>

#define S_LEN 512
#define BATCH 16
#define DIN   512
#define DF    512
#define NMIX  10
#define NCHAR 1024
#define DCTX  256
#define M_ROWS (S_LEN*BATCH)   // 8192

// d_out layout (tuple flattened in return order)
#define OFF_CTXOUT 0
#define OFF_ATTN   (S_LEN*BATCH*DCTX)
#define OFF_MEANS  (OFF_ATTN + S_LEN*BATCH*NCHAR)
#define OFF_VARS   (OFF_MEANS + S_LEN*BATCH*NMIX)
#define OFF_WTS    (OFF_VARS  + S_LEN*BATCH*NMIX)

// scratch layout in d_ws (byte offsets)
#define WS_W1T   0            // f16  512 KB (512x512, [n][k])
#define WS_W2T   (1u<<20)     // f32  64 KB  (32x512 padded, [j][k])
#define WS_DM    (2u<<20)     // f32  320 KB delta-means, chain-major [b][k][s]

typedef float    f32x16 __attribute__((ext_vector_type(16)));
typedef float    f32x4v __attribute__((ext_vector_type(4)));
typedef _Float16 f16x8  __attribute__((ext_vector_type(8)));

__device__ __forceinline__ unsigned short f2h(float x) {
    union { _Float16 h; unsigned short u; } cv;
    cv.h = (_Float16)x;
    return cv.u;
}
__device__ __forceinline__ ushort4 cvt4(float4 v) {
    ushort4 o; o.x = f2h(v.x); o.y = f2h(v.y); o.z = f2h(v.z); o.w = f2h(v.w);
    return o;
}
__device__ __forceinline__ void nt_store4(float* p, float a, float b, float c, float d) {
    f32x4v v; v.x = a; v.y = b; v.z = c; v.w = d;
    __builtin_nontemporal_store(v, (f32x4v*)p);
}

// ---------------------------------------------------------------------------
// Kernel 0 (tiny): W1 -> W1T f16 [n][k]; W2 -> W2T f32 [j][k] (32 rows, pad 0).
// X is NOT pre-converted: gemm12 reads each X element exactly once (M-tiled,
// N not tiled), so staging f32->f16 in-kernel is strictly cheaper than a
// round-trip through an Xh buffer.
// ---------------------------------------------------------------------------
__global__ __launch_bounds__(256) void convert_kernel(
    const float* __restrict__ W1, const float* __restrict__ W2,
    unsigned short* __restrict__ W1T, float* __restrict__ W2T)
{
    const int bid = blockIdx.x;
    const int tid = threadIdx.x;
    if (bid < 64) {
        __shared__ unsigned short tile[64*68];
        const int k0 = (bid >> 3) * 64, n0 = (bid & 7) * 64;
        #pragma unroll
        for (int q = 0; q < 4; q++) {
            const int r = q*16 + (tid >> 4);
            const int c = (tid & 15) * 4;
            float4 v = *(const float4*)(W1 + (size_t)(k0+r)*DF + n0 + c);
            *(ushort4*)(tile + r*68 + c) = cvt4(v);
        }
        __syncthreads();
        #pragma unroll
        for (int q = 0; q < 4; q++) {
            const int n  = q*16 + (tid >> 4);
            const int kq = (tid & 15) * 4;
            ushort4 o;
            o.x = tile[(kq+0)*68 + n];
            o.y = tile[(kq+1)*68 + n];
            o.z = tile[(kq+2)*68 + n];
            o.w = tile[(kq+3)*68 + n];
            *(ushort4*)(W1T + (size_t)(n0+n)*DIN + k0 + kq) = o;
        }
    } else {
        const int idx = (bid - 64)*256 + tid;   // 0..16383
        const int j = idx >> 9, k = idx & 511;
        W2T[idx] = (j < 30) ? W2[k*30 + j] : 0.f;
    }
}

// ---------------------------------------------------------------------------
// Kernel 1: fused GEMM1+GEMM2.  M-tile = 32 rows, full N = 512 in LDS.
// MFMA computes H-tile (32x512) in registers -> leakyrelu -> LDS (f16)
// -> VALU gemm2 tail (N=30) -> dmws/vars/wts.  H never touches HBM.
// 256 blocks x 512 threads (8 waves; wave w owns n in [w*64, w*64+64)).
// ---------------------------------------------------------------------------
__global__ __launch_bounds__(512) void gemm12_kernel(
    const float* __restrict__ X, const unsigned short* __restrict__ W1T,
    const float* __restrict__ b1,
    const float* __restrict__ W2T, const float* __restrict__ b2,
    float* __restrict__ dm_ws, float* __restrict__ dvars, float* __restrict__ dwts)
{
    __shared__ __align__(16) unsigned short As[32*64];     // 4 KB
    __shared__ __align__(16) unsigned short Bs[512*64];    // 64 KB (reused as Hs)
    const int tid  = threadIdx.x;
    const int r0   = blockIdx.x * 32;
    const int lane = tid & 63, w = tid >> 6;
    const int m = lane & 31, g = lane >> 5;
    // A staging: thread -> (row ra, f32 cols c4..c4+3)
    const int ra = tid >> 4, c4 = (tid & 15) * 4;
    const int sza = (ra & 7) << 3;
    // B staging: thread -> (row nb0 + u*64, 8-f16 granule cb)
    const int nb0 = tid >> 3, cb = (tid & 7) * 8;
    const int szm = (m & 7) << 3;

    f32x16 acc0 = {}, acc1 = {};
    const float* aptr = X + (size_t)(r0 + ra)*DIN + c4;

    for (int kt = 0; kt < DIN; kt += 64) {
        float4 av = *(const float4*)(aptr + kt);
        uint4 bv[8];
        #pragma unroll
        for (int u = 0; u < 8; u++)
            bv[u] = *(const uint4*)(W1T + (size_t)(nb0 + u*64)*DIN + kt + cb);
        __syncthreads();   // previous step's MFMA reads complete
        {
            ushort4 h = cvt4(av);
            *(ushort4*)(As + ra*64 + (((c4 & ~7) ^ sza)) + (c4 & 7)) = h;
        }
        #pragma unroll
        for (int u = 0; u < 8; u++) {
            const int n = nb0 + u*64;
            *(uint4*)(Bs + n*64 + (cb ^ ((n & 7) << 3))) = bv[u];
        }
        __syncthreads();
        #pragma unroll
        for (int ks = 0; ks < 64; ks += 16) {
            const int ac = ks + g*8;
            f16x8 af  = *(const f16x8*)(As + m*64 + (ac ^ szm));
            f16x8 bf0 = *(const f16x8*)(Bs + (w*64 + m)*64      + (ac ^ szm));
            f16x8 bf1 = *(const f16x8*)(Bs + (w*64 + 32 + m)*64 + (ac ^ szm));
            acc0 = __builtin_amdgcn_mfma_f32_32x32x16_f16(af, bf0, acc0, 0, 0, 0);
            acc1 = __builtin_amdgcn_mfma_f32_32x32x16_f16(af, bf1, acc1, 0, 0, 0);
        }
    }
    __syncthreads();   // all MFMA reads of Bs done; safe to overlay Hs
    unsigned short* Hs = Bs;   // [32][520] f16
    {
        const int nc0 = w*64 + m;
        const float bb0 = b1[nc0], bb1 = b1[nc0 + 32];
        #pragma unroll
        for (int r = 0; r < 16; r++) {
            const int rowloc = (r & 3) + 8*(r >> 2) + 4*g;
            float v0 = acc0[r] + bb0;
            float v1 = acc1[r] + bb1;
            v0 = v0 > 0.f ? v0 : 0.01f*v0;
            v1 = v1 > 0.f ? v1 : 0.01f*v1;
            Hs[rowloc*520 + nc0]      = f2h(v0);
            Hs[rowloc*520 + nc0 + 32] = f2h(v1);
        }
    }
    __syncthreads();
    // ---- gemm2 tail: 512 threads -> (r = tid&31, j0 = tid>>5 in 0..15) ----
    const int r = tid & 31, j0 = tid >> 5;
    const unsigned short* hrow = Hs + r*520;
    float a2[2] = {0.f, 0.f};
    for (int k0 = 0; k0 < DF; k0 += 8) {
        union { uint4 u; _Float16 h[8]; } hv;
        hv.u = *(const uint4*)(hrow + k0);
        float wv[2][8];
        #pragma unroll
        for (int q = 0; q < 2; q++) {
            *(float4*)(wv[q])     = *(const float4*)(W2T + (size_t)(j0 + q*16)*DF + k0);
            *(float4*)(wv[q] + 4) = *(const float4*)(W2T + (size_t)(j0 + q*16)*DF + k0 + 4);
        }
        #pragma unroll
        for (int i = 0; i < 8; i++) {
            float hf = (float)hv.h[i];
            a2[0] = fmaf(hf, wv[0][i], a2[0]);
            a2[1] = fmaf(hf, wv[1][i], a2[1]);
        }
    }
    const int row = r0 + r;
    #pragma unroll
    for (int q = 0; q < 2; q++) {
        const int j = j0 + q*16;
        if (j >= 30) continue;
        float dot = a2[q] + b2[j];
        float sp  = fmaxf(dot, 0.f) + log1pf(__expf(-fabsf(dot)));
        if (j < 10) {
            const int bb = row & (BATCH-1), s = row >> 4;
            dm_ws[((size_t)bb*NMIX + j)*S_LEN + s] = sp * (1.f/25.f);
        }
        else if (j < 20)  dvars[row*NMIX + (j-10)] = fminf(fmaxf(sp, 0.01f), 100.f);
        else              dwts [row*NMIX + (j-20)] = sp;
    }
}

// ---------------------------------------------------------------------------
// Kernel 2: fused scan + attention weights + attended contexts.
// Scan fixed vs round 1: carry up to s0 is a lane-PARALLEL sum reduction;
// only the 32-row window needs an actual prefix scan (5 shfl steps).
// ---------------------------------------------------------------------------
__global__ __launch_bounds__(512) void fused_kernel(
    const float* __restrict__ dm_ws, const float* __restrict__ init_means,
    const float* __restrict__ vars_g, const float* __restrict__ wts_g,
    const float* __restrict__ ctx,
    float* __restrict__ means_out, float* __restrict__ attn_out,
    float* __restrict__ ctxout)
{
    __shared__ float mlds[320];
    __shared__ float vlds[320];
    __shared__ float wlds[320];
    __shared__ float redbuf[8];
    __shared__ __align__(16) unsigned short As[32*64];
    __shared__ __align__(16) unsigned short Bs[256*64];

    const int bid = blockIdx.x;
    const int b   = bid >> 4;          // batch
    const int s0  = (bid & 15) * 32;   // first row of tile
    const int tid = threadIdx.x;
    const int lane = tid & 63, w = tid >> 6;   // 8 waves
    const int m = lane & 31, g = lane >> 5;

    // ---- carry (parallel sum over [0,s0)) + 32-window scan, per chain ----
    for (int k = w; k < NMIX; k += 8) {
        const float* chain = dm_ws + ((size_t)b*NMIX + k)*S_LEN;
        float part = 0.f;
        for (int s = lane; s < s0; s += 64) part += chain[s];
        #pragma unroll
        for (int d = 32; d >= 1; d >>= 1) part += __shfl_xor(part, d, 64);
        const float carry = init_means[b*NMIX + k] + part;
        float v = (lane < 32) ? chain[s0 + lane] : 0.f;
        #pragma unroll
        for (int d = 1; d < 32; d <<= 1) {
            float t = __shfl_up(v, d, 64);
            if (lane >= d) v += t;
        }
        if (lane < 32) mlds[lane*NMIX + k] = carry + v;
    }
    if (tid < 320) {
        const int s = tid / NMIX, k = tid - s*NMIX;
        const int row = (s0 + s)*BATCH + b;
        vlds[tid] = vars_g[row*NMIX + k];
        wlds[tid] = wts_g [row*NMIX + k];
    }
    __syncthreads();

    // ---- means output + local reach bound ----
    float reach = 0.f;
    if (tid < 320) {
        const int s = tid / NMIX, k = tid - s*NMIX;
        means_out[((s0 + s)*BATCH + b)*NMIX + k] = mlds[tid];
        reach = mlds[tid] + 4.8f * rsqrtf(vlds[tid]);
    }
    #pragma unroll
    for (int d = 32; d >= 1; d >>= 1) reach = fmaxf(reach, __shfl_xor(reach, d, 64));
    if (lane == 0) redbuf[w] = reach;
    __syncthreads();
    float rmax = redbuf[0];
    #pragma unroll
    for (int i = 1; i < 8; i++) rmax = fmaxf(rmax, redbuf[i]);
    const int kmax = min(NCHAR, (((int)rmax) + 64) & ~63);

    // ---- per-thread row params (row r fixed across chunks) ----
    const int r  = tid >> 4;       // 0..31
    const int ti = tid & 15;       // 0..15 -> 4 chars each
    float mr[NMIX], vr[NMIX], wr_[NMIX];
    #pragma unroll
    for (int k = 0; k < NMIX; k++) {
        mr[k] = mlds[r*NMIX + k];
        vr[k] = vlds[r*NMIX + k];
        wr_[k] = wlds[r*NMIX + k];
    }
    const size_t arow = (size_t)((s0 + r)*BATCH + b) * NCHAR;

    // ctx staging ids: thread covers (char-row tb, d = dq*32..+31)
    const int tb = tid & 63, dq = tid >> 6;
    const float* cbase = ctx + (size_t)b*DCTX + dq*32;
    const int szm = (m & 7) << 3;

    f32x16 acc = {};
    for (int kt = 0; kt < kmax; kt += 64) {
        // attention weights for t = kt + ti*4 .. +3 of row r
        float o[4];
        #pragma unroll
        for (int i = 0; i < 4; i++) {
            const float t = (float)(kt + ti*4 + i);
            float sum = 0.f;
            #pragma unroll
            for (int k = 0; k < NMIX; k++) {
                float d = t - mr[k];
                sum += wr_[k] * __expf(-d*d*vr[k]);
            }
            o[i] = sum;
        }
        // issue ctx loads before the barrier (latency overlap)
        float4 cf[8];
        #pragma unroll
        for (int u = 0; u < 8; u++)
            cf[u] = *(const float4*)(cbase + (size_t)(kt + tb)*(BATCH*DCTX) + u*4);
        __syncthreads();   // previous chunk's MFMA reads done
        nt_store4(attn_out + arow + kt + ti*4, o[0], o[1], o[2], o[3]);
        {
            ushort4 h; h.x = f2h(o[0]); h.y = f2h(o[1]); h.z = f2h(o[2]); h.w = f2h(o[3]);
            const int c = ti*4;
            *(ushort4*)(As + r*64 + ((c & ~7) ^ ((r&7)<<3)) + (c & 7)) = h;
        }
        {
            const int cb = (tb & ~7), cs = (tb & 7);
            #pragma unroll
            for (int u = 0; u < 8; u++) {
                ushort4 h = cvt4(cf[u]);
                const int n = dq*32 + u*4;
                Bs[(n+0)*64 + (cb ^ (((n+0)&7)<<3)) + cs] = h.x;
                Bs[(n+1)*64 + (cb ^ (((n+1)&7)<<3)) + cs] = h.y;
                Bs[(n+2)*64 + (cb ^ (((n+2)&7)<<3)) + cs] = h.z;
                Bs[(n+3)*64 + (cb ^ (((n+3)&7)<<3)) + cs] = h.w;
            }
        }
        __syncthreads();
        #pragma unroll
        for (int ks = 0; ks < 64; ks += 16) {
            const int ac = ks + g*8;
            f16x8 af = *(const f16x8*)(As + m*64 + (ac ^ szm));
            const int brow = w*32 + m;
            f16x8 bf = *(const f16x8*)(Bs + brow*64 + (ac ^ ((brow&7)<<3)));
            acc = __builtin_amdgcn_mfma_f32_32x32x16_f16(af, bf, acc, 0, 0, 0);
        }
    }
    // zero tail of attention output
    for (int t = kmax + ti*4; t < NCHAR; t += 64)
        nt_store4(attn_out + arow + t, 0.f, 0.f, 0.f, 0.f);

    // attended-context epilogue: wave w owns d = w*32 + m, all 32 rows
    #pragma unroll
    for (int rr = 0; rr < 16; rr++) {
        const int rowloc = (rr & 3) + 8*(rr >> 2) + 4*g;
        const int s = s0 + rowloc;
        __builtin_nontemporal_store(acc[rr],
            ctxout + ((size_t)s*BATCH + b)*DCTX + w*32 + m);
    }
}

// ---------------------------------------------------------------------------
extern "C" void kernel_launch(void* const* d_in, const int* in_sizes, int n_in,
                              void* d_out, int out_size, void* d_ws, size_t ws_size,
                              hipStream_t stream)
{
    const float* X     = (const float*)d_in[0];
    const float* ctx   = (const float*)d_in[1];
    const float* initm = (const float*)d_in[2];
    const float* W1    = (const float*)d_in[3];
    const float* b1    = (const float*)d_in[4];
    const float* W2    = (const float*)d_in[5];
    const float* b2    = (const float*)d_in[6];

    float* out      = (float*)d_out;
    float* out_ctx  = out + OFF_CTXOUT;
    float* out_attn = out + OFF_ATTN;
    float* out_mean = out + OFF_MEANS;
    float* out_var  = out + OFF_VARS;
    float* out_wts  = out + OFF_WTS;

    char* ws = (char*)d_ws;
    unsigned short* W1T  = (unsigned short*)(ws + WS_W1T);
    float*          W2T  = (float*)         (ws + WS_W2T);
    float*          dmws = (float*)         (ws + WS_DM);

    convert_kernel<<<128, 256, 0, stream>>>(W1, W2, W1T, W2T);
    gemm12_kernel<<<M_ROWS/32, 512, 0, stream>>>(X, W1T, b1, W2T, b2,
                                                 dmws, out_var, out_wts);
    fused_kernel<<<BATCH*16, 512, 0, stream>>>(dmws, initm, out_var, out_wts, ctx,
                                               out_mean, out_attn, out_ctx);
}

// Round 3
// 172.762 us; speedup vs baseline: 1.0142x; 1.0142x over previous
//
#include <hip/hip_runtime.h>
#include <math.h>

#define S_LEN 512
#define BATCH 16
#define DIN   512
#define DF    512
#define NMIX  10
#define NCHAR 1024
#define DCTX  256
#define M_ROWS (S_LEN*BATCH)   // 8192

// d_out layout (tuple flattened in return order)
#define OFF_CTXOUT 0
#define OFF_ATTN   (S_LEN*BATCH*DCTX)
#define OFF_MEANS  (OFF_ATTN + S_LEN*BATCH*NCHAR)
#define OFF_VARS   (OFF_MEANS + S_LEN*BATCH*NMIX)
#define OFF_WTS    (OFF_VARS  + S_LEN*BATCH*NMIX)

// scratch layout in d_ws (byte offsets)
#define WS_W1T   0            // f16  512 KB (512x512, [n][k])
#define WS_W2T   (1u<<20)     // f32  64 KB  (32x512 padded, [j][k])
#define WS_DM    (2u<<20)     // f32  320 KB delta-means, chain-major [b][k][s]

typedef float    f32x16 __attribute__((ext_vector_type(16)));
typedef float    f32x4v __attribute__((ext_vector_type(4)));
typedef _Float16 f16x8  __attribute__((ext_vector_type(8)));

__device__ __forceinline__ unsigned short f2h(float x) {
    union { _Float16 h; unsigned short u; } cv;
    cv.h = (_Float16)x;
    return cv.u;
}
__device__ __forceinline__ ushort4 cvt4(float4 v) {
    ushort4 o; o.x = f2h(v.x); o.y = f2h(v.y); o.z = f2h(v.z); o.w = f2h(v.w);
    return o;
}
__device__ __forceinline__ void nt_store4(float* p, float a, float b, float c, float d) {
    f32x4v v; v.x = a; v.y = b; v.z = c; v.w = d;
    __builtin_nontemporal_store(v, (f32x4v*)p);
}

// ---------------------------------------------------------------------------
// Kernel 0 (tiny): W1 -> W1T f16 [n][k]; W2 -> W2T f32 [j][k] (32 rows, pad 0).
// ---------------------------------------------------------------------------
__global__ __launch_bounds__(256) void convert_kernel(
    const float* __restrict__ W1, const float* __restrict__ W2,
    unsigned short* __restrict__ W1T, float* __restrict__ W2T)
{
    const int bid = blockIdx.x;
    const int tid = threadIdx.x;
    if (bid < 64) {
        __shared__ unsigned short tile[64*68];
        const int k0 = (bid >> 3) * 64, n0 = (bid & 7) * 64;
        #pragma unroll
        for (int q = 0; q < 4; q++) {
            const int r = q*16 + (tid >> 4);
            const int c = (tid & 15) * 4;
            float4 v = *(const float4*)(W1 + (size_t)(k0+r)*DF + n0 + c);
            *(ushort4*)(tile + r*68 + c) = cvt4(v);
        }
        __syncthreads();
        #pragma unroll
        for (int q = 0; q < 4; q++) {
            const int n  = q*16 + (tid >> 4);
            const int kq = (tid & 15) * 4;
            ushort4 o;
            o.x = tile[(kq+0)*68 + n];
            o.y = tile[(kq+1)*68 + n];
            o.z = tile[(kq+2)*68 + n];
            o.w = tile[(kq+3)*68 + n];
            *(ushort4*)(W1T + (size_t)(n0+n)*DIN + k0 + kq) = o;
        }
    } else {
        const int idx = (bid - 64)*256 + tid;   // 0..16383
        const int j = idx >> 9, k = idx & 511;
        W2T[idx] = (j < 30) ? W2[k*30 + j] : 0.f;
    }
}

// ---------------------------------------------------------------------------
// Kernel 1: fused GEMM1+GEMM2.  M-tile = 32 rows, full N = 512 in LDS.
// __launch_bounds__(512, 2): 2 waves/EU min -> 256-VGPR cap.  The bare (512)
// variant capped VGPR at 56 and spilled ~85 MB of scratch per dispatch
// (measured round 2) — that was the whole regression.
// ---------------------------------------------------------------------------
__global__ __launch_bounds__(512, 2) void gemm12_kernel(
    const float* __restrict__ X, const unsigned short* __restrict__ W1T,
    const float* __restrict__ b1,
    const float* __restrict__ W2T, const float* __restrict__ b2,
    float* __restrict__ dm_ws, float* __restrict__ dvars, float* __restrict__ dwts)
{
    __shared__ __align__(16) unsigned short As[32*64];     // 4 KB
    __shared__ __align__(16) unsigned short Bs[512*64];    // 64 KB (reused as Hs)
    const int tid  = threadIdx.x;
    const int r0   = blockIdx.x * 32;
    const int lane = tid & 63, w = tid >> 6;
    const int m = lane & 31, g = lane >> 5;
    // A staging: thread -> (row ra, f32 cols c4..c4+3)
    const int ra = tid >> 4, c4 = (tid & 15) * 4;
    const int sza = (ra & 7) << 3;
    // B staging: thread -> (row nb0 + u*64, 8-f16 granule cb)
    const int nb0 = tid >> 3, cb = (tid & 7) * 8;
    const int szm = (m & 7) << 3;

    f32x16 acc0 = {}, acc1 = {};
    const float* aptr = X + (size_t)(r0 + ra)*DIN + c4;

    for (int kt = 0; kt < DIN; kt += 64) {
        float4 av = *(const float4*)(aptr + kt);
        uint4 bv[8];
        #pragma unroll
        for (int u = 0; u < 8; u++)
            bv[u] = *(const uint4*)(W1T + (size_t)(nb0 + u*64)*DIN + kt + cb);
        __syncthreads();   // previous step's MFMA reads complete
        {
            ushort4 h = cvt4(av);
            *(ushort4*)(As + ra*64 + (((c4 & ~7) ^ sza)) + (c4 & 7)) = h;
        }
        #pragma unroll
        for (int u = 0; u < 8; u++) {
            const int n = nb0 + u*64;
            *(uint4*)(Bs + n*64 + (cb ^ ((n & 7) << 3))) = bv[u];
        }
        __syncthreads();
        #pragma unroll
        for (int ks = 0; ks < 64; ks += 16) {
            const int ac = ks + g*8;
            f16x8 af  = *(const f16x8*)(As + m*64 + (ac ^ szm));
            f16x8 bf0 = *(const f16x8*)(Bs + (w*64 + m)*64      + (ac ^ szm));
            f16x8 bf1 = *(const f16x8*)(Bs + (w*64 + 32 + m)*64 + (ac ^ szm));
            acc0 = __builtin_amdgcn_mfma_f32_32x32x16_f16(af, bf0, acc0, 0, 0, 0);
            acc1 = __builtin_amdgcn_mfma_f32_32x32x16_f16(af, bf1, acc1, 0, 0, 0);
        }
    }
    __syncthreads();   // all MFMA reads of Bs done; safe to overlay Hs
    unsigned short* Hs = Bs;   // [32][520] f16
    {
        const int nc0 = w*64 + m;
        const float bb0 = b1[nc0], bb1 = b1[nc0 + 32];
        #pragma unroll
        for (int r = 0; r < 16; r++) {
            const int rowloc = (r & 3) + 8*(r >> 2) + 4*g;
            float v0 = acc0[r] + bb0;
            float v1 = acc1[r] + bb1;
            v0 = v0 > 0.f ? v0 : 0.01f*v0;
            v1 = v1 > 0.f ? v1 : 0.01f*v1;
            Hs[rowloc*520 + nc0]      = f2h(v0);
            Hs[rowloc*520 + nc0 + 32] = f2h(v1);
        }
    }
    __syncthreads();
    // ---- gemm2 tail: 512 threads -> (r = tid&31, j0 = tid>>5 in 0..15) ----
    const int r = tid & 31, j0 = tid >> 5;
    const unsigned short* hrow = Hs + r*520;
    float a2[2] = {0.f, 0.f};
    for (int k0 = 0; k0 < DF; k0 += 8) {
        union { uint4 u; _Float16 h[8]; } hv;
        hv.u = *(const uint4*)(hrow + k0);
        float wv[2][8];
        #pragma unroll
        for (int q = 0; q < 2; q++) {
            *(float4*)(wv[q])     = *(const float4*)(W2T + (size_t)(j0 + q*16)*DF + k0);
            *(float4*)(wv[q] + 4) = *(const float4*)(W2T + (size_t)(j0 + q*16)*DF + k0 + 4);
        }
        #pragma unroll
        for (int i = 0; i < 8; i++) {
            float hf = (float)hv.h[i];
            a2[0] = fmaf(hf, wv[0][i], a2[0]);
            a2[1] = fmaf(hf, wv[1][i], a2[1]);
        }
    }
    const int row = r0 + r;
    #pragma unroll
    for (int q = 0; q < 2; q++) {
        const int j = j0 + q*16;
        if (j >= 30) continue;
        float dot = a2[q] + b2[j];
        float sp  = fmaxf(dot, 0.f) + log1pf(__expf(-fabsf(dot)));
        if (j < 10) {
            const int bb = row & (BATCH-1), s = row >> 4;
            dm_ws[((size_t)bb*NMIX + j)*S_LEN + s] = sp * (1.f/25.f);
        }
        else if (j < 20)  dvars[row*NMIX + (j-10)] = fminf(fmaxf(sp, 0.01f), 100.f);
        else              dwts [row*NMIX + (j-20)] = sp;
    }
}

// ---------------------------------------------------------------------------
// Kernel 2: fused scan + attention weights + attended contexts.
// Same (512, 2) fix: needs ~90 live VGPRs (16 acc + 30 mixture params +
// 32 ctx-prefetch), was silently spilling under the default 64-VGPR cap.
// ---------------------------------------------------------------------------
__global__ __launch_bounds__(512, 2) void fused_kernel(
    const float* __restrict__ dm_ws, const float* __restrict__ init_means,
    const float* __restrict__ vars_g, const float* __restrict__ wts_g,
    const float* __restrict__ ctx,
    float* __restrict__ means_out, float* __restrict__ attn_out,
    float* __restrict__ ctxout)
{
    __shared__ float mlds[320];
    __shared__ float vlds[320];
    __shared__ float wlds[320];
    __shared__ float redbuf[8];
    __shared__ __align__(16) unsigned short As[32*64];
    __shared__ __align__(16) unsigned short Bs[256*64];

    const int bid = blockIdx.x;
    const int b   = bid >> 4;          // batch
    const int s0  = (bid & 15) * 32;   // first row of tile
    const int tid = threadIdx.x;
    const int lane = tid & 63, w = tid >> 6;   // 8 waves
    const int m = lane & 31, g = lane >> 5;

    // ---- carry (parallel sum over [0,s0)) + 32-window scan, per chain ----
    for (int k = w; k < NMIX; k += 8) {
        const float* chain = dm_ws + ((size_t)b*NMIX + k)*S_LEN;
        float part = 0.f;
        for (int s = lane; s < s0; s += 64) part += chain[s];
        #pragma unroll
        for (int d = 32; d >= 1; d >>= 1) part += __shfl_xor(part, d, 64);
        const float carry = init_means[b*NMIX + k] + part;
        float v = (lane < 32) ? chain[s0 + lane] : 0.f;
        #pragma unroll
        for (int d = 1; d < 32; d <<= 1) {
            float t = __shfl_up(v, d, 64);
            if (lane >= d) v += t;
        }
        if (lane < 32) mlds[lane*NMIX + k] = carry + v;
    }
    if (tid < 320) {
        const int s = tid / NMIX, k = tid - s*NMIX;
        const int row = (s0 + s)*BATCH + b;
        vlds[tid] = vars_g[row*NMIX + k];
        wlds[tid] = wts_g [row*NMIX + k];
    }
    __syncthreads();

    // ---- means output + local reach bound ----
    float reach = 0.f;
    if (tid < 320) {
        const int s = tid / NMIX, k = tid - s*NMIX;
        means_out[((s0 + s)*BATCH + b)*NMIX + k] = mlds[tid];
        reach = mlds[tid] + 4.8f * rsqrtf(vlds[tid]);
    }
    #pragma unroll
    for (int d = 32; d >= 1; d >>= 1) reach = fmaxf(reach, __shfl_xor(reach, d, 64));
    if (lane == 0) redbuf[w] = reach;
    __syncthreads();
    float rmax = redbuf[0];
    #pragma unroll
    for (int i = 1; i < 8; i++) rmax = fmaxf(rmax, redbuf[i]);
    const int kmax = min(NCHAR, (((int)rmax) + 64) & ~63);

    // ---- per-thread row params (row r fixed across chunks) ----
    const int r  = tid >> 4;       // 0..31
    const int ti = tid & 15;       // 0..15 -> 4 chars each
    float mr[NMIX], vr[NMIX], wr_[NMIX];
    #pragma unroll
    for (int k = 0; k < NMIX; k++) {
        mr[k] = mlds[r*NMIX + k];
        vr[k] = vlds[r*NMIX + k];
        wr_[k] = wlds[r*NMIX + k];
    }
    const size_t arow = (size_t)((s0 + r)*BATCH + b) * NCHAR;

    // ctx staging ids: thread covers (char-row tb, d = dq*32..+31)
    const int tb = tid & 63, dq = tid >> 6;
    const float* cbase = ctx + (size_t)b*DCTX + dq*32;
    const int szm = (m & 7) << 3;

    f32x16 acc = {};
    for (int kt = 0; kt < kmax; kt += 64) {
        // attention weights for t = kt + ti*4 .. +3 of row r
        float o[4];
        #pragma unroll
        for (int i = 0; i < 4; i++) {
            const float t = (float)(kt + ti*4 + i);
            float sum = 0.f;
            #pragma unroll
            for (int k = 0; k < NMIX; k++) {
                float d = t - mr[k];
                sum += wr_[k] * __expf(-d*d*vr[k]);
            }
            o[i] = sum;
        }
        // issue ctx loads before the barrier (latency overlap)
        float4 cf[8];
        #pragma unroll
        for (int u = 0; u < 8; u++)
            cf[u] = *(const float4*)(cbase + (size_t)(kt + tb)*(BATCH*DCTX) + u*4);
        __syncthreads();   // previous chunk's MFMA reads done
        nt_store4(attn_out + arow + kt + ti*4, o[0], o[1], o[2], o[3]);
        {
            ushort4 h; h.x = f2h(o[0]); h.y = f2h(o[1]); h.z = f2h(o[2]); h.w = f2h(o[3]);
            const int c = ti*4;
            *(ushort4*)(As + r*64 + ((c & ~7) ^ ((r&7)<<3)) + (c & 7)) = h;
        }
        {
            const int cb = (tb & ~7), cs = (tb & 7);
            #pragma unroll
            for (int u = 0; u < 8; u++) {
                ushort4 h = cvt4(cf[u]);
                const int n = dq*32 + u*4;
                Bs[(n+0)*64 + (cb ^ (((n+0)&7)<<3)) + cs] = h.x;
                Bs[(n+1)*64 + (cb ^ (((n+1)&7)<<3)) + cs] = h.y;
                Bs[(n+2)*64 + (cb ^ (((n+2)&7)<<3)) + cs] = h.z;
                Bs[(n+3)*64 + (cb ^ (((n+3)&7)<<3)) + cs] = h.w;
            }
        }
        __syncthreads();
        #pragma unroll
        for (int ks = 0; ks < 64; ks += 16) {
            const int ac = ks + g*8;
            f16x8 af = *(const f16x8*)(As + m*64 + (ac ^ szm));
            const int brow = w*32 + m;
            f16x8 bf = *(const f16x8*)(Bs + brow*64 + (ac ^ ((brow&7)<<3)));
            acc = __builtin_amdgcn_mfma_f32_32x32x16_f16(af, bf, acc, 0, 0, 0);
        }
    }
    // zero tail of attention output
    for (int t = kmax + ti*4; t < NCHAR; t += 64)
        nt_store4(attn_out + arow + t, 0.f, 0.f, 0.f, 0.f);

    // attended-context epilogue: wave w owns d = w*32 + m, all 32 rows
    #pragma unroll
    for (int rr = 0; rr < 16; rr++) {
        const int rowloc = (rr & 3) + 8*(rr >> 2) + 4*g;
        const int s = s0 + rowloc;
        __builtin_nontemporal_store(acc[rr],
            ctxout + ((size_t)s*BATCH + b)*DCTX + w*32 + m);
    }
}

// ---------------------------------------------------------------------------
extern "C" void kernel_launch(void* const* d_in, const int* in_sizes, int n_in,
                              void* d_out, int out_size, void* d_ws, size_t ws_size,
                              hipStream_t stream)
{
    const float* X     = (const float*)d_in[0];
    const float* ctx   = (const float*)d_in[1];
    const float* initm = (const float*)d_in[2];
    const float* W1    = (const float*)d_in[3];
    const float* b1    = (const float*)d_in[4];
    const float* W2    = (const float*)d_in[5];
    const float* b2    = (const float*)d_in[6];

    float* out      = (float*)d_out;
    float* out_ctx  = out + OFF_CTXOUT;
    float* out_attn = out + OFF_ATTN;
    float* out_mean = out + OFF_MEANS;
    float* out_var  = out + OFF_VARS;
    float* out_wts  = out + OFF_WTS;

    char* ws = (char*)d_ws;
    unsigned short* W1T  = (unsigned short*)(ws + WS_W1T);
    float*          W2T  = (float*)         (ws + WS_W2T);
    float*          dmws = (float*)         (ws + WS_DM);

    convert_kernel<<<128, 256, 0, stream>>>(W1, W2, W1T, W2T);
    gemm12_kernel<<<M_ROWS/32, 512, 0, stream>>>(X, W1T, b1, W2T, b2,
                                                 dmws, out_var, out_wts);
    fused_kernel<<<BATCH*16, 512, 0, stream>>>(dmws, initm, out_var, out_wts, ctx,
                                               out_mean, out_attn, out_ctx);
}

// Round 4
// 144.174 us; speedup vs baseline: 1.2153x; 1.1983x over previous
//
#include <hip/hip_runtime.h>
#include <math.h>

#define S_LEN 512
#define BATCH 16
#define DIN   512
#define DF    512
#define NMIX  10
#define NCHAR 1024
#define DCTX  256
#define M_ROWS (S_LEN*BATCH)   // 8192

// d_out layout (tuple flattened in return order)
#define OFF_CTXOUT 0
#define OFF_ATTN   (S_LEN*BATCH*DCTX)
#define OFF_MEANS  (OFF_ATTN + S_LEN*BATCH*NCHAR)
#define OFF_VARS   (OFF_MEANS + S_LEN*BATCH*NMIX)
#define OFF_WTS    (OFF_VARS  + S_LEN*BATCH*NMIX)

// scratch layout in d_ws (byte offsets)
#define WS_XH    0            // f16  8 MB   (8192x512)
#define WS_W1T   (8u<<20)     // f16  512 KB (512x512, [n][k] TRANSPOSED)
#define WS_W2T   (9u<<20)     // f32  64 KB  (32x512 padded)
#define WS_HH    (10u<<20)    // f16  8 MB
#define WS_ATTNH (26u<<20)    // f16  16.8 MB
#define WS_BOUND (44u<<20)    // u32  512 B  per-(batch, 64-row-tile) bound (float bits)

#define NX4     1048576       // X float4 count
#define CVT_BLOCKS (NX4/256)  // 4096
#define W1T_BLOCKS 64
#define W2T_BLOCKS 64

typedef float    f32x16 __attribute__((ext_vector_type(16)));
typedef float    f32x4v __attribute__((ext_vector_type(4)));
typedef _Float16 f16x8  __attribute__((ext_vector_type(8)));

__device__ __forceinline__ unsigned short f2h(float x) {
    union { _Float16 h; unsigned short u; } cv;
    cv.h = (_Float16)x;
    return cv.u;
}
__device__ __forceinline__ ushort4 cvt4(float4 v) {
    ushort4 o; o.x = f2h(v.x); o.y = f2h(v.y); o.z = f2h(v.z); o.w = f2h(v.w);
    return o;
}
__device__ __forceinline__ void nt_store4(float* p, float a, float b, float c, float d) {
    f32x4v v; v.x = a; v.y = b; v.z = c; v.w = d;
    __builtin_nontemporal_store(v, (f32x4v*)p);
}

// ---------------------------------------------------------------------------
// Kernel 0: convert X -> f16; W1 -> f16 TRANSPOSED [n][k]; W2^T fp32;
// zero bound[128].
// ---------------------------------------------------------------------------
__global__ __launch_bounds__(256) void convert_kernel(
    const float* __restrict__ X, const float* __restrict__ W1,
    const float* __restrict__ W2,
    unsigned short* __restrict__ Xh, unsigned short* __restrict__ W1T,
    float* __restrict__ W2T, unsigned int* __restrict__ bound)
{
    const int bid = blockIdx.x;
    const int tid = threadIdx.x;
    if (bid < CVT_BLOCKS) {
        const int i4 = bid*256 + tid;
        ((ushort4*)Xh)[i4] = cvt4(((const float4*)X)[i4]);
    } else if (bid < CVT_BLOCKS + W1T_BLOCKS) {
        __shared__ unsigned short tile[64*68];
        const int b2 = bid - CVT_BLOCKS;
        const int k0 = (b2 >> 3) * 64, n0 = (b2 & 7) * 64;
        #pragma unroll
        for (int q = 0; q < 4; q++) {
            const int r = q*16 + (tid >> 4);
            const int c = (tid & 15) * 4;
            float4 v = *(const float4*)(W1 + (size_t)(k0+r)*DF + n0 + c);
            *(ushort4*)(tile + r*68 + c) = cvt4(v);
        }
        __syncthreads();
        #pragma unroll
        for (int q = 0; q < 4; q++) {
            const int n  = q*16 + (tid >> 4);
            const int kq = (tid & 15) * 4;
            ushort4 o;
            o.x = tile[(kq+0)*68 + n];
            o.y = tile[(kq+1)*68 + n];
            o.z = tile[(kq+2)*68 + n];
            o.w = tile[(kq+3)*68 + n];
            *(ushort4*)(W1T + (size_t)(n0+n)*DIN + k0 + kq) = o;
        }
    } else if (bid < CVT_BLOCKS + W1T_BLOCKS + W2T_BLOCKS) {
        const int idx = (bid - CVT_BLOCKS - W1T_BLOCKS)*256 + tid;
        if (idx < 512*32) {
            const int j = idx >> 9, k = idx & 511;
            W2T[idx] = (j < 30) ? W2[k*30 + j] : 0.f;
        }
    } else {
        if (tid < BATCH*8) bound[tid] = 0u;
    }
}

// ---------------------------------------------------------------------------
// Kernel 1: GEMM1 via f16 MFMA 32x32x16, 64x64 tiles, k-major operands.
// ---------------------------------------------------------------------------
__global__ __launch_bounds__(256) void gemm1_kernel(
    const unsigned short* __restrict__ Xh, const unsigned short* __restrict__ W1T,
    const float* __restrict__ b1, unsigned short* __restrict__ Hh)
{
    __shared__ __align__(16) unsigned short As[64*72];
    __shared__ __align__(16) unsigned short Bs[64*72];
    const int row0 = (blockIdx.x >> 3) * 64;
    const int n0   = (blockIdx.x & 7)  * 64;
    const int tid  = threadIdx.x;
    const int lane = tid & 63, w = tid >> 6;
    const int wr = (w >> 1) * 32, wc = (w & 1) * 32;
    const int m  = lane & 31,  g  = lane >> 5;
    const int sa = tid >> 2,   ka = (tid & 3) * 16;

    f32x16 acc = {};
    const unsigned short* aptr = Xh  + (size_t)(row0+sa)*DIN + ka;
    const unsigned short* bptr = W1T + (size_t)(n0 +sa)*DIN + ka;

    for (int kt = 0; kt < DIN; kt += 64) {
        uint4 av0 = *(const uint4*)(aptr + kt);
        uint4 av1 = *(const uint4*)(aptr + kt + 8);
        uint4 bv0 = *(const uint4*)(bptr + kt);
        uint4 bv1 = *(const uint4*)(bptr + kt + 8);
        __syncthreads();
        *(uint4*)(As + sa*72 + ka)     = av0;
        *(uint4*)(As + sa*72 + ka + 8) = av1;
        *(uint4*)(Bs + sa*72 + ka)     = bv0;
        *(uint4*)(Bs + sa*72 + ka + 8) = bv1;
        __syncthreads();
        #pragma unroll
        for (int ks = 0; ks < 64; ks += 16) {
            f16x8 af = *(const f16x8*)(As + (wr+m)*72 + ks + g*8);
            f16x8 bf = *(const f16x8*)(Bs + (wc+m)*72 + ks + g*8);
            acc = __builtin_amdgcn_mfma_f32_32x32x16_f16(af, bf, acc, 0, 0, 0);
        }
    }
    const int ncol = n0 + wc + m;
    const float bb = b1[ncol];
    #pragma unroll
    for (int r = 0; r < 16; r++) {
        const int rowloc = (r & 3) + 8*(r >> 2) + 4*g;
        const int row = row0 + wr + rowloc;
        float v = acc[r] + bb;
        v = v > 0.f ? v : 0.01f * v;
        Hh[(size_t)row*DF + ncol] = f2h(v);
    }
}

// ---------------------------------------------------------------------------
// Kernel 2: GEMM2 (8192x30, K=512); LDS-staged H, broadcast W2T reads.
// ---------------------------------------------------------------------------
__global__ __launch_bounds__(256) void gemm2_kernel(
    const unsigned short* __restrict__ Hh, const float* __restrict__ W2T,
    const float* __restrict__ b2,
    float* __restrict__ dmeans, float* __restrict__ dvars, float* __restrict__ dwts)
{
    __shared__ __align__(16) unsigned short Hs[32*520];
    const int tid = threadIdx.x;
    const int r0  = blockIdx.x * 32;
    {
        const uint4* src = (const uint4*)(Hh + (size_t)r0*DF);
        #pragma unroll
        for (int i = 0; i < 8; i++) {
            int u   = tid + i*256;
            int row = u >> 6;
            int col = (u & 63) * 8;
            *(uint4*)(Hs + row*520 + col) = src[u];
        }
    }
    __syncthreads();

    const int r  = tid & 31;
    const int j0 = tid >> 5;
    const unsigned short* hrow = Hs + r*520;
    float acc[4] = {0.f, 0.f, 0.f, 0.f};

    for (int k0 = 0; k0 < DF; k0 += 8) {
        union { uint4 u; _Float16 h[8]; } hv;
        hv.u = *(const uint4*)(hrow + k0);
        float wv[4][8];
        #pragma unroll
        for (int q = 0; q < 4; q++) {
            *(float4*)(wv[q])     = *(const float4*)(W2T + (size_t)(j0 + q*8)*DF + k0);
            *(float4*)(wv[q] + 4) = *(const float4*)(W2T + (size_t)(j0 + q*8)*DF + k0 + 4);
        }
        #pragma unroll
        for (int i = 0; i < 8; i++) {
            float hf = (float)hv.h[i];
            acc[0] = fmaf(hf, wv[0][i], acc[0]);
            acc[1] = fmaf(hf, wv[1][i], acc[1]);
            acc[2] = fmaf(hf, wv[2][i], acc[2]);
            acc[3] = fmaf(hf, wv[3][i], acc[3]);
        }
    }
    const int row = r0 + r;
    #pragma unroll
    for (int q = 0; q < 4; q++) {
        const int j = j0 + q*8;
        if (j >= 30) continue;
        float dot = acc[q] + b2[j];
        float sp  = fmaxf(dot, 0.f) + log1pf(__expf(-fabsf(dot)));
        if (j < 10)       dmeans[row*NMIX + j]      = sp / 25.0f;
        else if (j < 20)  dvars [row*NMIX + (j-10)] = fminf(fmaxf(sp, 0.01f), 100.f);
        else              dwts  [row*NMIX + (j-20)] = sp;
    }
}

// ---------------------------------------------------------------------------
// Kernel 3: scan (in-place on means region) + per-(batch, 64-row tile) reach
// bound.  Wave wid covers s in [wid*64, wid*64+64) -> one atomic per wave
// into bound[b*8 + wid].  Tighter than round-0's global per-batch bound:
// means are nondecreasing in s (delta = softplus >= 0), so early tiles get
// small kmax.
// ---------------------------------------------------------------------------
__global__ __launch_bounds__(512) void scan_kernel(
    const float* __restrict__ init_means, float* __restrict__ means,
    const float* __restrict__ vars_g, unsigned int* __restrict__ bound)
{
    const int p    = blockIdx.x;       // p = b*NMIX + k
    const int s    = threadIdx.x;
    const int lane = s & 63;
    const int wid  = s >> 6;

    float x = means[s*(BATCH*NMIX) + p];
    #pragma unroll
    for (int d = 1; d < 64; d <<= 1) {
        float tv = __shfl_up(x, d, 64);
        if (lane >= d) x += tv;
    }
    __shared__ float wsum[8];
    if (lane == 63) wsum[wid] = x;
    __syncthreads();
    float off = init_means[p];
    for (int i = 0; i < wid; i++) off += wsum[i];
    x += off;
    means[s*(BATCH*NMIX) + p] = x;

    float v = vars_g[s*(BATCH*NMIX) + p];
    float reach = x + 4.8f * rsqrtf(v);
    #pragma unroll
    for (int d = 32; d >= 1; d >>= 1)
        reach = fmaxf(reach, __shfl_xor(reach, d, 64));
    if (lane == 0)
        atomicMax((int*)&bound[(p / NMIX) * 8 + wid], __float_as_int(reach));
}

// ---------------------------------------------------------------------------
// Kernel 4: attention weights.  Zero fast-path beyond the row's TILE bound;
// f32 output via non-temporal stores; attnh only t < kmax.
// ---------------------------------------------------------------------------
__global__ __launch_bounds__(256) void attn_kernel(
    const float* __restrict__ means, const float* __restrict__ vars,
    const float* __restrict__ wts,   const unsigned int* __restrict__ bound,
    float* __restrict__ attn, unsigned short* __restrict__ attnh)
{
    const int row = blockIdx.x;              // row = s*BATCH + b
    const int b   = row & (BATCH-1);
    const int tid = threadIdx.x;
    const int bd  = (int)__int_as_float((int)bound[b*8 + (row >> 10)]);  // s>>6
    const int kmax = min(NCHAR, (bd + 64) & ~63);
    const int t0  = tid * 4;

    float o[4] = {0.f, 0.f, 0.f, 0.f};
    if (t0 <= bd) {
        float m[NMIX], v[NMIX], w[NMIX];
        #pragma unroll
        for (int k = 0; k < NMIX; k++) {
            m[k] = means[row*NMIX + k];
            v[k] = vars [row*NMIX + k];
            w[k] = wts  [row*NMIX + k];
        }
        #pragma unroll
        for (int i = 0; i < 4; i++) {
            const float t = (float)(t0 + i);
            float sum = 0.f;
            #pragma unroll
            for (int k = 0; k < NMIX; k++) {
                float d = t - m[k];
                sum += w[k] * __expf(-d*d*v[k]);
            }
            o[i] = sum;
        }
    }
    nt_store4(attn + (size_t)row*NCHAR + t0, o[0], o[1], o[2], o[3]);
    if (t0 < kmax) {
        ushort4 h; h.x = f2h(o[0]); h.y = f2h(o[1]); h.z = f2h(o[2]); h.w = f2h(o[3]);
        *(ushort4*)(attnh + (size_t)row*NCHAR + t0) = h;
    }
}

// ---------------------------------------------------------------------------
// Kernel 5: attended contexts via f16 MFMA; K-loop clipped to the s-tile's
// kmax (same tile bound the attn rows used -> attnh coverage consistent).
// ---------------------------------------------------------------------------
__global__ __launch_bounds__(256) void ctx_mfma_kernel(
    const unsigned short* __restrict__ attnh, const float* __restrict__ ctx,
    const unsigned int* __restrict__ bound, float* __restrict__ out)
{
    __shared__ __align__(16) unsigned short As[64*72];
    __shared__ __align__(16) unsigned short Bs[64*72];
    const int bid  = blockIdx.x;
    const int b    = bid >> 5;
    const int rem  = bid & 31;
    const int s0   = (rem >> 2) * 64;
    const int d0   = (rem & 3)  * 64;
    const int tid  = threadIdx.x;
    const int lane = tid & 63, w = tid >> 6;
    const int wr = (w >> 1) * 32, wc = (w & 1) * 32;
    const int m  = lane & 31,  g  = lane >> 5;
    const int sl = tid >> 2,   tq = (tid & 3) * 16;
    const int tb = tid & 63,   db = (tid >> 6) * 16;

    const int bd   = (int)__int_as_float((int)bound[b*8 + (rem >> 2)]);  // s0>>6
    const int kmax = min(NCHAR, (bd + 64) & ~63);

    f32x16 acc = {};
    const unsigned short* abase = attnh + (size_t)(s0+sl)*(BATCH*NCHAR) + b*NCHAR + tq;
    const float*          bbase = ctx   + (size_t)b*DCTX + d0 + db;

    for (int kt = 0; kt < kmax; kt += 64) {
        uint4 a0  = *(const uint4*)(abase + kt);
        uint4 a1  = *(const uint4*)(abase + kt + 8);
        float4 bf0 = *(const float4*)(bbase + (size_t)(kt+tb)*(BATCH*DCTX));
        float4 bf1 = *(const float4*)(bbase + (size_t)(kt+tb)*(BATCH*DCTX) + 4);
        float4 bf2 = *(const float4*)(bbase + (size_t)(kt+tb)*(BATCH*DCTX) + 8);
        float4 bf3 = *(const float4*)(bbase + (size_t)(kt+tb)*(BATCH*DCTX) + 12);
        __syncthreads();
        *(uint4*)(As + sl*72 + tq)     = a0;
        *(uint4*)(As + sl*72 + tq + 8) = a1;
        {
            ushort4 h0 = cvt4(bf0), h1 = cvt4(bf1), h2 = cvt4(bf2), h3 = cvt4(bf3);
            Bs[(db + 0)*72 + tb] = h0.x;  Bs[(db + 1)*72 + tb] = h0.y;
            Bs[(db + 2)*72 + tb] = h0.z;  Bs[(db + 3)*72 + tb] = h0.w;
            Bs[(db + 4)*72 + tb] = h1.x;  Bs[(db + 5)*72 + tb] = h1.y;
            Bs[(db + 6)*72 + tb] = h1.z;  Bs[(db + 7)*72 + tb] = h1.w;
            Bs[(db + 8)*72 + tb] = h2.x;  Bs[(db + 9)*72 + tb] = h2.y;
            Bs[(db +10)*72 + tb] = h2.z;  Bs[(db +11)*72 + tb] = h2.w;
            Bs[(db +12)*72 + tb] = h3.x;  Bs[(db +13)*72 + tb] = h3.y;
            Bs[(db +14)*72 + tb] = h3.z;  Bs[(db +15)*72 + tb] = h3.w;
        }
        __syncthreads();
        #pragma unroll
        for (int ks = 0; ks < 64; ks += 16) {
            f16x8 af = *(const f16x8*)(As + (wr+m)*72 + ks + g*8);
            f16x8 bf = *(const f16x8*)(Bs + (wc+m)*72 + ks + g*8);
            acc = __builtin_amdgcn_mfma_f32_32x32x16_f16(af, bf, acc, 0, 0, 0);
        }
    }
    #pragma unroll
    for (int r = 0; r < 16; r++) {
        int rowloc = (r & 3) + 8*(r >> 2) + 4*g;
        int s = s0 + wr + rowloc;
        __builtin_nontemporal_store(acc[r],
            out + (size_t)s*(BATCH*DCTX) + b*DCTX + d0 + wc + m);
    }
}

// ---------------------------------------------------------------------------
extern "C" void kernel_launch(void* const* d_in, const int* in_sizes, int n_in,
                              void* d_out, int out_size, void* d_ws, size_t ws_size,
                              hipStream_t stream)
{
    const float* X     = (const float*)d_in[0];
    const float* ctx   = (const float*)d_in[1];
    const float* initm = (const float*)d_in[2];
    const float* W1    = (const float*)d_in[3];
    const float* b1    = (const float*)d_in[4];
    const float* W2    = (const float*)d_in[5];
    const float* b2    = (const float*)d_in[6];

    float* out      = (float*)d_out;
    float* out_ctx  = out + OFF_CTXOUT;
    float* out_attn = out + OFF_ATTN;
    float* out_mean = out + OFF_MEANS;
    float* out_var  = out + OFF_VARS;
    float* out_wts  = out + OFF_WTS;

    char* ws = (char*)d_ws;
    unsigned short* Xh    = (unsigned short*)(ws + WS_XH);
    unsigned short* W1T   = (unsigned short*)(ws + WS_W1T);
    float*          W2T   = (float*)         (ws + WS_W2T);
    unsigned short* Hh    = (unsigned short*)(ws + WS_HH);
    unsigned short* attnh = (unsigned short*)(ws + WS_ATTNH);
    unsigned int*   bnd   = (unsigned int*)  (ws + WS_BOUND);

    convert_kernel<<<CVT_BLOCKS + W1T_BLOCKS + W2T_BLOCKS + 1, 256, 0, stream>>>(
        X, W1, W2, Xh, W1T, W2T, bnd);
    gemm1_kernel<<<(M_ROWS/64)*(DF/64), 256, 0, stream>>>(Xh, W1T, b1, Hh);
    gemm2_kernel<<<M_ROWS/32, 256, 0, stream>>>(Hh, W2T, b2, out_mean, out_var, out_wts);
    scan_kernel<<<BATCH*NMIX, 512, 0, stream>>>(initm, out_mean, out_var, bnd);
    attn_kernel<<<M_ROWS, 256, 0, stream>>>(out_mean, out_var, out_wts, bnd,
                                            out_attn, attnh);
    ctx_mfma_kernel<<<16*8*4, 256, 0, stream>>>(attnh, ctx, bnd, out_ctx);
}